// Round 4
// baseline (672.081 us; speedup 1.0000x reference)
//
#include <hip/hip_runtime.h>
#include <hip/hip_cooperative_groups.h>

namespace cg = cooperative_groups;

// Problem constants (fixed by the reference)
#define B_   2
#define DZ   41
#define HY   400
#define WX   352
#define NVOX 40000
#define PD   43      // DZ+2
#define PH   402     // HY+2
#define PW   354     // WX+2
#define DO_  21
#define HO_  200
#define WO_  176
#define C1   128
#define GRID_CELLS (B_*PD*PH*PW)        // 12,238,488 (even)
#define OUT_POS    (B_*DO_*HO_*WO_)     // 1,478,400 (div by 4)
#define OUT_BYTES  ((size_t)OUT_POS * 32 * sizeof(float))   // 189,235,200 B
#define NCHUNK     ((NVOX + 15) / 16)   // 2500

// Journal:
// R4 306.5 / R5 306.0 / R6 316.1 / R7(=R8 file) 327.1 -> every kernel-level
// "optimization" was neutral; every ADDED dispatch cost ~+10us. Compute-side
// estimates: all kernels sum to ~100-150us. Conclusion: timed window is
// dominated by dispatch serialization (10 launches) + harness poison fills.
// R9: ONE cooperative kernel, grid.sync() between phases; memsets become
// in-kernel streaming zeros; nbr fused into subm1 (list persisted for subm2).
// Fallback to the proven multi-dispatch path if coop launch fails.
// Predict ~200-230us; if still ~300, floor is harness-side -> roofline.

// ---- valid downsample taps for one axis, from PADDED input coord ----
// ref: o = pcoord - doff (doff in 0..2), valid iff o even and 0 <= o/2 < outdim.
__device__ __forceinline__ int axis_taps(int pcoord, int outdim, int* ds, int* ps) {
    if (pcoord & 1) { ds[0] = 1; ps[0] = pcoord >> 1; return 1; }
    int h = pcoord >> 1, nu = 0;
    if (h < outdim) { ds[nu] = 0; ps[nu] = h; nu++; }
    ds[nu] = 2; ps[nu] = h - 1; nu++;
    return nu;
}

// ======================= single cooperative mega-kernel =======================
__global__ void k_all(const float* __restrict__ feat, const int* __restrict__ coors,
                      const float* __restrict__ W1, const float* __restrict__ W2,
                      const float* __restrict__ W3,
                      unsigned short* __restrict__ grid_, int* __restrict__ list,
                      int* __restrict__ cnt, float* __restrict__ x1,
                      float* __restrict__ x2, unsigned char* __restrict__ flag,
                      float* __restrict__ out)
{
    cg::grid_group gg = cg::this_grid();
    const int tid = blockIdx.x * blockDim.x + threadIdx.x;
    const int gsz = gridDim.x * blockDim.x;

    __shared__ int   s_list[16][28];
    __shared__ int   s_cnt[16];
    __shared__ float s_w2[27*256];   // 27.6 KB; total LDS ~29.5 KB/block

    // ---- P0: zero grid, out, flag (streaming stores) ----
    {
        unsigned int* g32 = (unsigned int*)grid_;
        for (int i = tid; i < GRID_CELLS/2; i += gsz) g32[i] = 0u;
        float4 z4 = make_float4(0.f, 0.f, 0.f, 0.f);
        float4* o4 = (float4*)out;
        for (int i = tid; i < OUT_POS*8; i += gsz) o4[i] = z4;
        unsigned int* fl = (unsigned int*)flag;
        for (int i = tid; i < OUT_POS/4; i += gsz) fl[i] = 0u;
    }
    gg.sync();

    // ---- P1: build padded grid of (voxel id + 1) ----
    for (int n = tid; n < NVOX; n += gsz) {
        int b = coors[4*n+0], z = coors[4*n+1], y = coors[4*n+2], x = coors[4*n+3];
        grid_[((b*PD + z+1)*PH + y+1)*PW + x+1] = (unsigned short)(n + 1);
    }
    gg.sync();

    // ---- P2: derive compacted neighbor lists + subm1 (128->16, ReLU) ----
    for (int cb = blockIdx.x; cb < NCHUNK; cb += gridDim.x) {
        int base = cb * 16;
        if (threadIdx.x < 16) {
            int n = base + threadIdx.x;
            int c = 0;
            if (n < NVOX) {
                int b = coors[4*n+0], z = coors[4*n+1], y = coors[4*n+2], x = coors[4*n+3];
                #pragma unroll
                for (int dz = 0; dz < 3; ++dz)
                #pragma unroll
                for (int dy = 0; dy < 3; ++dy) {
                    const unsigned short* row = grid_ + ((size_t)(b*PD + z+dz)*PH + (y+dy))*PW + x;
                    #pragma unroll
                    for (int dx = 0; dx < 3; ++dx) {
                        int id = (int)row[dx] - 1;
                        if (id >= 0) s_list[threadIdx.x][c++] = ((dz*9 + dy*3 + dx) << 16) | id;
                    }
                }
                cnt[n] = c;                                  // persist for P3
                for (int t = 0; t < c; ++t) list[n*27 + t] = s_list[threadIdx.x][t];
            }
            s_cnt[threadIdx.x] = c;
        }
        __syncthreads();
        int v = threadIdx.x >> 4, d = threadIdx.x & 15;
        int n = base + v;
        if (n < NVOX) {
            int m = s_cnt[v];
            float a0 = 0.f, a1 = 0.f, a2 = 0.f, a3 = 0.f;
            for (int t = 0; t < m; ++t) {
                int e = s_list[v][t];
                int k = e >> 16, idx = e & 0xFFFF;
                const float4* f4 = (const float4*)(feat + (size_t)idx * C1);
                const float* w = W1 + k * (C1*16) + d;       // W1[k][c][d]
                #pragma unroll
                for (int c4 = 0; c4 < 32; ++c4) {
                    float4 fv = f4[c4];
                    const float* wp = w + c4 * 64;
                    a0 += fv.x * wp[0];
                    a1 += fv.y * wp[16];
                    a2 += fv.z * wp[32];
                    a3 += fv.w * wp[48];
                }
            }
            x1[n*16 + d] = fmaxf((a0 + a1) + (a2 + a3), 0.f);
        }
        __syncthreads();   // s_list reused next chunk
    }
    gg.sync();

    // ---- P3: subm2 (16->16, ReLU), W2 in LDS ----
    for (int i = threadIdx.x; i < 27*256; i += blockDim.x) s_w2[i] = W2[i];
    for (int cb = blockIdx.x; cb < NCHUNK; cb += gridDim.x) {
        int base = cb * 16;
        __syncthreads();   // covers s_w2 first iter + s_list reuse
        if (threadIdx.x < 16) {
            int n = base + threadIdx.x;
            s_cnt[threadIdx.x] = (n < NVOX) ? cnt[n] : 0;
        }
        for (int i = threadIdx.x; i < 16*27; i += blockDim.x) {
            int v = i / 27, k = i % 27;
            int n = base + v;
            s_list[v][k] = (n < NVOX) ? list[n*27 + k] : 0;   // entries >= cnt unused
        }
        __syncthreads();
        int v = threadIdx.x >> 4, d = threadIdx.x & 15;
        int n = base + v;
        if (n < NVOX) {
            int m = s_cnt[v];
            float a0 = 0.f, a1 = 0.f, a2 = 0.f, a3 = 0.f;
            for (int t = 0; t < m; ++t) {
                int e = s_list[v][t];
                int k = e >> 16, idx = e & 0xFFFF;
                const float4* x4 = (const float4*)(x1 + (size_t)idx * 16);
                float4 xa = x4[0], xb = x4[1], xc = x4[2], xd = x4[3];
                const float* wp = s_w2 + k * 256 + d;
                a0 += xa.x * wp[0*16]  + xa.y * wp[1*16]  + xa.z * wp[2*16]  + xa.w * wp[3*16];
                a1 += xb.x * wp[4*16]  + xb.y * wp[5*16]  + xb.z * wp[6*16]  + xb.w * wp[7*16];
                a2 += xc.x * wp[8*16]  + xc.y * wp[9*16]  + xc.z * wp[10*16] + xc.w * wp[11*16];
                a3 += xd.x * wp[12*16] + xd.y * wp[13*16] + xd.z * wp[14*16] + xd.w * wp[15*16];
            }
            x2[n*16 + d] = fmaxf((a0 + a1) + (a2 + a3), 0.f);
        }
    }
    gg.sync();

    // ---- P4: stride-2 conv 16->32 scatter (32 lanes per voxel) + flag ----
    for (int nn = (tid >> 5); nn < NVOX; nn += (gsz >> 5)) {
        int d = threadIdx.x & 31;
        int b  = coors[4*nn+0];
        int zp = coors[4*nn+1] + 1, yp = coors[4*nn+2] + 1, xp = coors[4*nn+3] + 1;
        int dzv[2], pzv[2], dyv[2], pyv[2], dxv[2], pxv[2];
        int nz = axis_taps(zp, DO_, dzv, pzv);
        int ny = axis_taps(yp, HO_, dyv, pyv);
        int nx = axis_taps(xp, WO_, dxv, pxv);
        const float4* xr = (const float4*)(x2 + (size_t)nn * 16);
        float r[16];
        *(float4*)(r + 0)  = xr[0];
        *(float4*)(r + 4)  = xr[1];
        *(float4*)(r + 8)  = xr[2];
        *(float4*)(r + 12) = xr[3];
        int bofs = b * (DO_*HO_*WO_);
        for (int iz = 0; iz < nz; ++iz)
            for (int iy = 0; iy < ny; ++iy)
                for (int ix = 0; ix < nx; ++ix) {
                    int k = dzv[iz]*9 + dyv[iy]*3 + dxv[ix];
                    int p = bofs + (pzv[iz]*HO_ + pyv[iy])*WO_ + pxv[ix];
                    const float* w = W3 + k*512 + d;   // W3[k][c][d]
                    float acc = 0.f;
                    #pragma unroll
                    for (int c = 0; c < 16; ++c) acc += r[c] * w[c * 32];
                    atomicAdd(out + (size_t)p * 32 + d, acc);
                    if (d == 0) flag[p] = 1;           // benign race
                }
    }
    gg.sync();

    // ---- P5: ReLU over flagged positions ----
    for (int p = tid; p < OUT_POS; p += gsz) {
        if (!flag[p]) continue;
        float4* o = (float4*)(out + (size_t)p * 32);
        #pragma unroll
        for (int j = 0; j < 8; ++j) {
            float4 vv = o[j];
            vv.x = fmaxf(vv.x, 0.f); vv.y = fmaxf(vv.y, 0.f);
            vv.z = fmaxf(vv.z, 0.f); vv.w = fmaxf(vv.w, 0.f);
            o[j] = vv;
        }
    }
}

// ======================= fallback multi-dispatch path (proven R6 kernels) =====
__global__ void k_build(const int* __restrict__ coors, unsigned short* __restrict__ grid_) {
    int n = blockIdx.x * blockDim.x + threadIdx.x;
    if (n >= NVOX) return;
    int b = coors[4*n+0], z = coors[4*n+1], y = coors[4*n+2], x = coors[4*n+3];
    grid_[((b*PD + z+1)*PH + y+1)*PW + x+1] = (unsigned short)(n + 1);
}

__global__ void k_nbr(const int* __restrict__ coors, const unsigned short* __restrict__ grid_,
                      int* __restrict__ list, int* __restrict__ cnt) {
    int n = blockIdx.x * blockDim.x + threadIdx.x;
    if (n >= NVOX) return;
    int b = coors[4*n+0], z = coors[4*n+1], y = coors[4*n+2], x = coors[4*n+3];
    int c = 0;
    int* lp = list + n * 27;
    #pragma unroll
    for (int dz = 0; dz < 3; ++dz)
    #pragma unroll
    for (int dy = 0; dy < 3; ++dy) {
        const unsigned short* row = grid_ + ((size_t)(b*PD + z+dz)*PH + (y+dy))*PW + x;
        #pragma unroll
        for (int dx = 0; dx < 3; ++dx) {
            int id = (int)row[dx] - 1;
            if (id >= 0) lp[c++] = ((dz*9 + dy*3 + dx) << 16) | id;
        }
    }
    cnt[n] = c;
}

__global__ void k_subm1(const float* __restrict__ feat, const float* __restrict__ W1,
                        const int* __restrict__ list, const int* __restrict__ cnt,
                        float* __restrict__ x1) {
    __shared__ int s_list[16][28];
    __shared__ int s_cnt[16];
    int base = blockIdx.x * 16;
    if (threadIdx.x < 16) {
        int n = base + threadIdx.x;
        s_cnt[threadIdx.x] = (n < NVOX) ? cnt[n] : 0;
    }
    for (int i = threadIdx.x; i < 16*27; i += 256) {
        int v = i / 27, k = i % 27;
        int n = base + v;
        s_list[v][k] = (n < NVOX) ? list[n*27 + k] : 0;
    }
    __syncthreads();
    int v = threadIdx.x >> 4, d = threadIdx.x & 15;
    int n = base + v;
    if (n >= NVOX) return;
    int m = s_cnt[v];
    float a0 = 0.f, a1 = 0.f, a2 = 0.f, a3 = 0.f;
    for (int t = 0; t < m; ++t) {
        int e = s_list[v][t];
        int k = e >> 16, idx = e & 0xFFFF;
        const float4* f4 = (const float4*)(feat + (size_t)idx * C1);
        const float* w = W1 + k * (C1*16) + d;
        #pragma unroll
        for (int c4 = 0; c4 < 32; ++c4) {
            float4 fv = f4[c4];
            const float* wp = w + c4 * 64;
            a0 += fv.x * wp[0]; a1 += fv.y * wp[16];
            a2 += fv.z * wp[32]; a3 += fv.w * wp[48];
        }
    }
    x1[n*16 + d] = fmaxf((a0 + a1) + (a2 + a3), 0.f);
}

__global__ void k_subm2(const float* __restrict__ x1, const float* __restrict__ W2,
                        const int* __restrict__ list, const int* __restrict__ cnt,
                        float* __restrict__ x2) {
    __shared__ int   s_list[16][28];
    __shared__ int   s_cnt[16];
    __shared__ float s_w2[27*256];
    for (int i = threadIdx.x; i < 27*256; i += 256) s_w2[i] = W2[i];
    int base = blockIdx.x * 16;
    if (threadIdx.x < 16) {
        int n = base + threadIdx.x;
        s_cnt[threadIdx.x] = (n < NVOX) ? cnt[n] : 0;
    }
    for (int i = threadIdx.x; i < 16*27; i += 256) {
        int v = i / 27, k = i % 27;
        int n = base + v;
        s_list[v][k] = (n < NVOX) ? list[n*27 + k] : 0;
    }
    __syncthreads();
    int v = threadIdx.x >> 4, d = threadIdx.x & 15;
    int n = base + v;
    if (n >= NVOX) return;
    int m = s_cnt[v];
    float a0 = 0.f, a1 = 0.f, a2 = 0.f, a3 = 0.f;
    for (int t = 0; t < m; ++t) {
        int e = s_list[v][t];
        int k = e >> 16, idx = e & 0xFFFF;
        const float4* x4 = (const float4*)(x1 + (size_t)idx * 16);
        float4 xa = x4[0], xb = x4[1], xc = x4[2], xd = x4[3];
        const float* wp = s_w2 + k * 256 + d;
        a0 += xa.x * wp[0*16]  + xa.y * wp[1*16]  + xa.z * wp[2*16]  + xa.w * wp[3*16];
        a1 += xb.x * wp[4*16]  + xb.y * wp[5*16]  + xb.z * wp[6*16]  + xb.w * wp[7*16];
        a2 += xc.x * wp[8*16]  + xc.y * wp[9*16]  + xc.z * wp[10*16] + xc.w * wp[11*16];
        a3 += xd.x * wp[12*16] + xd.y * wp[13*16] + xd.z * wp[14*16] + xd.w * wp[15*16];
    }
    x2[n*16 + d] = fmaxf((a0 + a1) + (a2 + a3), 0.f);
}

__global__ void k_scatter(const float* __restrict__ x2, const float* __restrict__ W3,
                          const int* __restrict__ coors, float* __restrict__ out,
                          unsigned char* __restrict__ flag) {
    int v = threadIdx.x >> 5, d = threadIdx.x & 31;
    int n = blockIdx.x * 8 + v;
    if (n >= NVOX) return;
    int b  = coors[4*n+0];
    int zp = coors[4*n+1] + 1, yp = coors[4*n+2] + 1, xp = coors[4*n+3] + 1;
    int dzv[2], pzv[2], dyv[2], pyv[2], dxv[2], pxv[2];
    int nz = axis_taps(zp, DO_, dzv, pzv);
    int ny = axis_taps(yp, HO_, dyv, pyv);
    int nx = axis_taps(xp, WO_, dxv, pxv);
    const float4* xr = (const float4*)(x2 + (size_t)n * 16);
    float r[16];
    *(float4*)(r + 0)  = xr[0];
    *(float4*)(r + 4)  = xr[1];
    *(float4*)(r + 8)  = xr[2];
    *(float4*)(r + 12) = xr[3];
    int bofs = b * (DO_*HO_*WO_);
    for (int iz = 0; iz < nz; ++iz)
        for (int iy = 0; iy < ny; ++iy)
            for (int ix = 0; ix < nx; ++ix) {
                int k = dzv[iz]*9 + dyv[iy]*3 + dxv[ix];
                int p = bofs + (pzv[iz]*HO_ + pyv[iy])*WO_ + pxv[ix];
                const float* w = W3 + k*512 + d;
                float acc = 0.f;
                #pragma unroll
                for (int c = 0; c < 16; ++c) acc += r[c] * w[c * 32];
                atomicAdd(out + (size_t)p * 32 + d, acc);
                if (d == 0) flag[p] = 1;
            }
}

__global__ void k_relu_flag(const unsigned char* __restrict__ flag, float* __restrict__ out) {
    int p = blockIdx.x * blockDim.x + threadIdx.x;
    if (p >= OUT_POS) return;
    if (!flag[p]) return;
    float4* o = (float4*)(out + (size_t)p * 32);
    #pragma unroll
    for (int j = 0; j < 8; ++j) {
        float4 v = o[j];
        v.x = fmaxf(v.x, 0.f); v.y = fmaxf(v.y, 0.f);
        v.z = fmaxf(v.z, 0.f); v.w = fmaxf(v.w, 0.f);
        o[j] = v;
    }
}

extern "C" void kernel_launch(void* const* d_in, const int* in_sizes, int n_in,
                              void* d_out, int out_size, void* d_ws, size_t ws_size,
                              hipStream_t stream) {
    const float* feat  = (const float*)d_in[0];  // f32 (N,128)
    const int*   coors = (const int*)d_in[1];    // int32 (N,4)
    const float* W1    = (const float*)d_in[2];  // f32 (27,128,16)
    const float* W2    = (const float*)d_in[3];  // f32 (27,16,16)
    const float* W3    = (const float*)d_in[4];  // f32 (27,16,32)
    float* out = (float*)d_out;                  // f32 (2,21,200,176,32)

    char* ws = (char*)d_ws;
    size_t off = 0;
    unsigned short* grid = (unsigned short*)(ws + off);
    off += (((size_t)GRID_CELLS*2) + 255) & ~(size_t)255;
    int* list = (int*)(ws + off); off += (((size_t)NVOX*27*4) + 255) & ~(size_t)255;
    int* cnt  = (int*)(ws + off); off += (((size_t)NVOX*4)    + 255) & ~(size_t)255;
    float* x1 = (float*)(ws + off); off += (((size_t)NVOX*16*4) + 255) & ~(size_t)255;
    float* x2 = (float*)(ws + off); off += (((size_t)NVOX*16*4) + 255) & ~(size_t)255;
    unsigned char* flag = (unsigned char*)(ws + off); off += ((size_t)OUT_POS + 255) & ~(size_t)255;

    // Query cooperative capacity once (host-side query, graph-capture safe).
    static int coop_blocks = -2;   // -2 unqueried, -1 disabled
    if (coop_blocks == -2) {
        int per_cu = 0;
        hipError_t e = hipOccupancyMaxActiveBlocksPerMultiprocessor(&per_cu, k_all, 256, 0);
        coop_blocks = (e == hipSuccess && per_cu >= 1) ? per_cu * 256 : -1;  // 256 CUs
    }

    bool ok = false;
    if (coop_blocks > 0) {
        void* args[] = { (void*)&feat, (void*)&coors, (void*)&W1, (void*)&W2, (void*)&W3,
                         (void*)&grid, (void*)&list, (void*)&cnt, (void*)&x1, (void*)&x2,
                         (void*)&flag, (void*)&out };
        hipError_t e = hipLaunchCooperativeKernel((const void*)k_all, dim3(coop_blocks),
                                                  dim3(256), args, 0, stream);
        ok = (e == hipSuccess);
        if (!ok) coop_blocks = -1;   // don't retry; use fallback from now on
    }

    if (!ok) {
        hipMemsetAsync(grid, 0x00, (size_t)GRID_CELLS * 2, stream);
        hipMemsetAsync(flag, 0x00, (size_t)OUT_POS, stream);
        hipMemsetAsync(out, 0x00, OUT_BYTES, stream);
        k_build<<<(NVOX + 255) / 256, 256, 0, stream>>>(coors, grid);
        k_nbr<<<(NVOX + 255) / 256, 256, 0, stream>>>(coors, grid, list, cnt);
        k_subm1<<<(NVOX + 15) / 16, 256, 0, stream>>>(feat, W1, list, cnt, x1);
        k_subm2<<<(NVOX + 15) / 16, 256, 0, stream>>>(x1, W2, list, cnt, x2);
        k_scatter<<<(NVOX + 7) / 8, 256, 0, stream>>>(x2, W3, coors, out, flag);
        k_relu_flag<<<(OUT_POS + 255) / 256, 256, 0, stream>>>(flag, out);
    }
}

// Round 5
// 349.540 us; speedup vs baseline: 1.9228x; 1.9228x over previous
//
#include <hip/hip_runtime.h>

// Problem constants (fixed by the reference)
#define B_   2
#define DZ   41
#define HY   400
#define WX   352
#define NVOX 40000
#define PD   43      // DZ+2
#define PH   402     // HY+2
#define PW   354     // WX+2
#define DO_  21
#define HO_  200
#define WO_  176
#define C1   128
#define GRID_CELLS (B_*PD*PH*PW)        // 12,238,488
#define OUT_POS    (B_*DO_*HO_*WO_)     // 1,478,400
#define NCHUNK     ((NVOX + 15) / 16)   // 2500
#define W1_ELEMS   (27*C1*16)           // 55296
#define W3_ELEMS   (27*16*32)           // 13824

// Journal:
// R4 306.5 / R5 306.0 / R6 316.1 / R7 327.1: kernel-level tweaks neutral;
//   top-5 always harness poison fills (757MB @113us).
// R9 coop mega-kernel: 672us, k_all=780us, VALU 2.6%, HBM 5% -> grid.sync()
//   latency-bound disaster, but gave traffic ground truth: ~300MB total.
//   Model: timed = 113us in-window poison + ours (fits 306 AND 672).
// R10: revert to multi-dispatch; 9 nodes -> 6 (memset grid+flag merged;
//   build+transposes fused; nbr+subm1 fused incl. zero-touched-out + flag;
//   memset(out)+relu -> dense k_finalize). W1t/W3t transposes make all
//   weight loads float4. Predict ~250us; if >=300, floor is harness-side.

// ---- valid downsample taps for one axis, from PADDED input coord ----
__device__ __forceinline__ int axis_taps(int pcoord, int outdim, int* ds, int* ps) {
    if (pcoord & 1) { ds[0] = 1; ps[0] = pcoord >> 1; return 1; }
    int h = pcoord >> 1, nu = 0;
    if (h < outdim) { ds[nu] = 0; ps[nu] = h; nu++; }
    ds[nu] = 2; ps[nu] = h - 1; nu++;
    return nu;
}

// ---- node 2: build padded grid (+1 ids) AND transpose W1,W3 ----
// W1[k][c][d] -> W1t[k][d][c]; W3[k][c][d] -> W3t[k][d][c]
__global__ void k_build(const int* __restrict__ coors,
                        const float* __restrict__ W1, const float* __restrict__ W3,
                        unsigned short* __restrict__ grid_,
                        float* __restrict__ W1t, float* __restrict__ W3t) {
    int i = blockIdx.x * blockDim.x + threadIdx.x;
    if (i < NVOX) {
        int b = coors[4*i+0], z = coors[4*i+1], y = coors[4*i+2], x = coors[4*i+3];
        grid_[((b*PD + z+1)*PH + y+1)*PW + x+1] = (unsigned short)(i + 1);
    } else if (i < NVOX + W1_ELEMS) {
        int j = i - NVOX;
        int k = j >> 11, r = j & 2047, c = r >> 4, d = r & 15;   // j = k*2048 + c*16 + d
        W1t[((size_t)k*16 + d)*C1 + c] = W1[j];
    } else if (i < NVOX + W1_ELEMS + W3_ELEMS) {
        int j = i - NVOX - W1_ELEMS;
        int k = j >> 9, r = j & 511, c = r >> 5, d = r & 31;     // j = k*512 + c*32 + d
        W3t[((size_t)k*32 + d)*16 + c] = W3[j];
    }
}

// ---- node 3: fused neighbor-derive + subm1 (128->16, ReLU)
//      + pre-zero touched out positions + set flag ----
__global__ void k_nbr_subm1(const float* __restrict__ feat, const int* __restrict__ coors,
                            const unsigned short* __restrict__ grid_,
                            const float* __restrict__ W1t,
                            int* __restrict__ list, int* __restrict__ cnt,
                            float* __restrict__ x1,
                            unsigned char* __restrict__ flag, float* __restrict__ out) {
    __shared__ int s_list[16][28];
    __shared__ int s_cnt[16];
    __shared__ int s_pos[16][8];
    __shared__ int s_np[16];
    int base = blockIdx.x * 16;
    if (threadIdx.x < 16) {
        int n = base + threadIdx.x;
        int c = 0, np = 0;
        if (n < NVOX) {
            int b = coors[4*n+0], z = coors[4*n+1], y = coors[4*n+2], x = coors[4*n+3];
            // 27-neighbor compacted list
            #pragma unroll
            for (int dz = 0; dz < 3; ++dz)
            #pragma unroll
            for (int dy = 0; dy < 3; ++dy) {
                const unsigned short* row = grid_ + ((size_t)(b*PD + z+dz)*PH + (y+dy))*PW + x;
                #pragma unroll
                for (int dx = 0; dx < 3; ++dx) {
                    int id = (int)row[dx] - 1;
                    if (id >= 0) s_list[threadIdx.x][c++] = ((dz*9 + dy*3 + dx) << 16) | id;
                }
            }
            cnt[n] = c;
            int* lp = list + n * 27;
            for (int t = 0; t < c; ++t) lp[t] = s_list[threadIdx.x][t];
            // downsample target positions (for pre-zero + flag)
            int zp = z + 1, yp = y + 1, xp = x + 1;
            int dzv[2], pzv[2], dyv[2], pyv[2], dxv[2], pxv[2];
            int nz = axis_taps(zp, DO_, dzv, pzv);
            int ny = axis_taps(yp, HO_, dyv, pyv);
            int nx = axis_taps(xp, WO_, dxv, pxv);
            int bofs = b * (DO_*HO_*WO_);
            for (int iz = 0; iz < nz; ++iz)
                for (int iy = 0; iy < ny; ++iy)
                    for (int ix = 0; ix < nx; ++ix) {
                        int p = bofs + (pzv[iz]*HO_ + pyv[iy])*WO_ + pxv[ix];
                        s_pos[threadIdx.x][np++] = p;
                        flag[p] = 1;                       // benign race
                    }
        }
        s_cnt[threadIdx.x] = c;
        s_np[threadIdx.x]  = np;
    }
    __syncthreads();
    int v = threadIdx.x >> 4, d = threadIdx.x & 15;
    int n = base + v;
    if (n >= NVOX) return;
    // pre-zero touched out positions: 16 lanes x float2 = 128B per position
    int np = s_np[v];
    for (int t = 0; t < np; ++t) {
        int p = s_pos[v][t];
        ((float2*)(out + (size_t)p * 32))[d] = make_float2(0.f, 0.f);  // benign race
    }
    // subm1: valid taps only; feat and weights both float4
    int m = s_cnt[v];
    float a0 = 0.f, a1 = 0.f, a2 = 0.f, a3 = 0.f;
    for (int t = 0; t < m; ++t) {
        int e = s_list[v][t];
        int k = e >> 16, idx = e & 0xFFFF;
        const float4* f4 = (const float4*)(feat + (size_t)idx * C1);
        const float4* w4 = (const float4*)(W1t + ((size_t)k*16 + d)*C1);
        #pragma unroll
        for (int c4 = 0; c4 < 32; ++c4) {
            float4 fv = f4[c4], wv = w4[c4];
            a0 += fv.x * wv.x;
            a1 += fv.y * wv.y;
            a2 += fv.z * wv.z;
            a3 += fv.w * wv.w;
        }
    }
    x1[n*16 + d] = fmaxf((a0 + a1) + (a2 + a3), 0.f);
}

// ---- node 4: subm2 (16->16, ReLU), W2 in LDS ----
__global__ void k_subm2(const float* __restrict__ x1, const float* __restrict__ W2,
                        const int* __restrict__ list, const int* __restrict__ cnt,
                        float* __restrict__ x2) {
    __shared__ int   s_list[16][28];
    __shared__ int   s_cnt[16];
    __shared__ float s_w2[27*256];
    for (int i = threadIdx.x; i < 27*256; i += 256) s_w2[i] = W2[i];
    int base = blockIdx.x * 16;
    if (threadIdx.x < 16) {
        int n = base + threadIdx.x;
        s_cnt[threadIdx.x] = (n < NVOX) ? cnt[n] : 0;
    }
    for (int i = threadIdx.x; i < 16*27; i += 256) {
        int v = i / 27, k = i % 27;
        int n = base + v;
        s_list[v][k] = (n < NVOX) ? list[n*27 + k] : 0;
    }
    __syncthreads();
    int v = threadIdx.x >> 4, d = threadIdx.x & 15;
    int n = base + v;
    if (n >= NVOX) return;
    int m = s_cnt[v];
    float a0 = 0.f, a1 = 0.f, a2 = 0.f, a3 = 0.f;
    for (int t = 0; t < m; ++t) {
        int e = s_list[v][t];
        int k = e >> 16, idx = e & 0xFFFF;
        const float4* x4 = (const float4*)(x1 + (size_t)idx * 16);
        float4 xa = x4[0], xb = x4[1], xc = x4[2], xd = x4[3];
        const float* wp = s_w2 + k * 256 + d;
        a0 += xa.x * wp[0*16]  + xa.y * wp[1*16]  + xa.z * wp[2*16]  + xa.w * wp[3*16];
        a1 += xb.x * wp[4*16]  + xb.y * wp[5*16]  + xb.z * wp[6*16]  + xb.w * wp[7*16];
        a2 += xc.x * wp[8*16]  + xc.y * wp[9*16]  + xc.z * wp[10*16] + xc.w * wp[11*16];
        a3 += xd.x * wp[12*16] + xd.y * wp[13*16] + xd.z * wp[14*16] + xd.w * wp[15*16];
    }
    x2[n*16 + d] = fmaxf((a0 + a1) + (a2 + a3), 0.f);
}

// ---- node 5: stride-2 conv 16->32 scatter (atomic into pre-zeroed slots) ----
__global__ void k_scatter(const float* __restrict__ x2, const float* __restrict__ W3t,
                          const int* __restrict__ coors, float* __restrict__ out) {
    int v = threadIdx.x >> 5, d = threadIdx.x & 31;
    int n = blockIdx.x * 8 + v;
    if (n >= NVOX) return;
    int b  = coors[4*n+0];
    int zp = coors[4*n+1] + 1, yp = coors[4*n+2] + 1, xp = coors[4*n+3] + 1;
    int dzv[2], pzv[2], dyv[2], pyv[2], dxv[2], pxv[2];
    int nz = axis_taps(zp, DO_, dzv, pzv);
    int ny = axis_taps(yp, HO_, dyv, pyv);
    int nx = axis_taps(xp, WO_, dxv, pxv);
    const float4* xr = (const float4*)(x2 + (size_t)n * 16);
    float4 r0 = xr[0], r1 = xr[1], r2 = xr[2], r3 = xr[3];
    int bofs = b * (DO_*HO_*WO_);
    for (int iz = 0; iz < nz; ++iz)
        for (int iy = 0; iy < ny; ++iy)
            for (int ix = 0; ix < nx; ++ix) {
                int k = dzv[iz]*9 + dyv[iy]*3 + dxv[ix];
                int p = bofs + (pzv[iz]*HO_ + pyv[iy])*WO_ + pxv[ix];
                const float4* w4 = (const float4*)(W3t + ((size_t)k*32 + d)*16);
                float4 w0 = w4[0], w1 = w4[1], w2 = w4[2], w3 = w4[3];
                float acc = r0.x*w0.x + r0.y*w0.y + r0.z*w0.z + r0.w*w0.w
                          + r1.x*w1.x + r1.y*w1.y + r1.z*w1.z + r1.w*w1.w
                          + r2.x*w2.x + r2.y*w2.y + r2.z*w2.z + r2.w*w2.w
                          + r3.x*w3.x + r3.y*w3.y + r3.z*w3.z + r3.w*w3.w;
                atomicAdd(out + (size_t)p * 32 + d, acc);
            }
}

// ---- node 6: dense finalize: touched -> relu in place, untouched -> 0 ----
__global__ void k_finalize(const unsigned char* __restrict__ flag, float* __restrict__ out) {
    int p = blockIdx.x * blockDim.x + threadIdx.x;
    if (p >= OUT_POS) return;
    float4* o = (float4*)(out + (size_t)p * 32);
    if (flag[p]) {
        #pragma unroll
        for (int j = 0; j < 8; ++j) {
            float4 v = o[j];
            v.x = fmaxf(v.x, 0.f); v.y = fmaxf(v.y, 0.f);
            v.z = fmaxf(v.z, 0.f); v.w = fmaxf(v.w, 0.f);
            o[j] = v;
        }
    } else {
        float4 z = make_float4(0.f, 0.f, 0.f, 0.f);
        #pragma unroll
        for (int j = 0; j < 8; ++j) o[j] = z;
    }
}

extern "C" void kernel_launch(void* const* d_in, const int* in_sizes, int n_in,
                              void* d_out, int out_size, void* d_ws, size_t ws_size,
                              hipStream_t stream) {
    const float* feat  = (const float*)d_in[0];  // f32 (N,128)
    const int*   coors = (const int*)d_in[1];    // int32 (N,4)
    const float* W1    = (const float*)d_in[2];  // f32 (27,128,16)
    const float* W2    = (const float*)d_in[3];  // f32 (27,16,16)
    const float* W3    = (const float*)d_in[4];  // f32 (27,16,32)
    float* out = (float*)d_out;                  // f32 (2,21,200,176,32)

    char* ws = (char*)d_ws;
    size_t off = 0;
    // grid and flag adjacent -> single memset covers both
    unsigned short* grid = (unsigned short*)(ws + off);
    off += (((size_t)GRID_CELLS*2) + 255) & ~(size_t)255;
    unsigned char* flag = (unsigned char*)(ws + off);
    off += ((size_t)OUT_POS + 255) & ~(size_t)255;
    size_t zero_span = off;                      // grid + flag
    int* list = (int*)(ws + off); off += (((size_t)NVOX*27*4) + 255) & ~(size_t)255;
    int* cnt  = (int*)(ws + off); off += (((size_t)NVOX*4)    + 255) & ~(size_t)255;
    float* x1 = (float*)(ws + off); off += (((size_t)NVOX*16*4) + 255) & ~(size_t)255;
    float* x2 = (float*)(ws + off); off += (((size_t)NVOX*16*4) + 255) & ~(size_t)255;
    float* W1t = (float*)(ws + off); off += (((size_t)W1_ELEMS*4) + 255) & ~(size_t)255;
    float* W3t = (float*)(ws + off); off += (((size_t)W3_ELEMS*4) + 255) & ~(size_t)255;

    hipMemsetAsync(ws, 0x00, zero_span, stream);                 // grid=0, flag=0
    k_build<<<(NVOX + W1_ELEMS + W3_ELEMS + 255) / 256, 256, 0, stream>>>(
        coors, W1, W3, grid, W1t, W3t);
    k_nbr_subm1<<<NCHUNK, 256, 0, stream>>>(feat, coors, grid, W1t, list, cnt, x1, flag, out);
    k_subm2<<<NCHUNK, 256, 0, stream>>>(x1, W2, list, cnt, x2);
    k_scatter<<<(NVOX + 7) / 8, 256, 0, stream>>>(x2, W3t, coors, out);
    k_finalize<<<(OUT_POS + 255) / 256, 256, 0, stream>>>(flag, out);
}

// Round 6
// 306.185 us; speedup vs baseline: 2.1950x; 1.1416x over previous
//
#include <hip/hip_runtime.h>

// Problem constants (fixed by the reference)
#define B_   2
#define DZ   41
#define HY   400
#define WX   352
#define NVOX 40000
#define PD   43      // DZ+2
#define PH   402     // HY+2
#define PW   354     // WX+2
#define DO_  21
#define HO_  200
#define WO_  176
#define C1   128
#define GRID_CELLS (B_*PD*PH*PW)        // 12,238,488
#define OUT_POS    (B_*DO_*HO_*WO_)     // 1,478,400
#define OUT_BYTES  ((size_t)OUT_POS * 32 * sizeof(float))   // 189,235,200 B

// Journal (session):
// R4 306.5 / R5 306.0 (proven best) / R6 compaction 316.1 / R7 +nodes 327.1 /
// R9 coop mega-kernel 672.1 / R10 6-node custom-finalize 349.5.
// Model fitting ALL rounds: timed = ~226us harness poison fills (2x ~113us,
// 82-85% HBM peak, visible as 739,200KB fillBufferAligned in every top-5;
// untouchable) + ours. Ours in this structure ~80us, matching bottom-up floor:
// out memset 30 (at fill rate) + grid memset 4 + gather/atomic kernels ~25 +
// 8 launches ~20. Every structural change regressed -> RESTORE proven best.
// If this reproduces ~306, declare roofline: remaining time is harness-fixed
// memory-bound fill + our floor.

// ---- build padded dense grid of (voxel id + 1), 0 = empty ----
__global__ void k_build(const int* __restrict__ coors, unsigned short* __restrict__ grid) {
    int n = blockIdx.x * blockDim.x + threadIdx.x;
    if (n >= NVOX) return;
    int b = coors[4*n+0], z = coors[4*n+1], y = coors[4*n+2], x = coors[4*n+3];
    grid[((b*PD + z+1)*PH + y+1)*PW + x+1] = (unsigned short)(n + 1);
}

// ---- precompute 27-neighbor table (used by both subm convs) ----
__global__ void k_nbr(const int* __restrict__ coors, const unsigned short* __restrict__ grid,
                      int* __restrict__ nbr) {
    int i = blockIdx.x * blockDim.x + threadIdx.x;
    if (i >= NVOX * 27) return;
    int n = i / 27, k = i % 27;
    int b = coors[4*n+0], z = coors[4*n+1], y = coors[4*n+2], x = coors[4*n+3];
    int dz = k / 9, dy = (k / 3) % 3, dx = k % 3;
    nbr[i] = (int)grid[((b*PD + z+dz)*PH + y+dy)*PW + x+dx] - 1;
}

// ---- subm conv 1: 128 -> 16, ReLU, fp32 out ----
__global__ void k_subm1(const float* __restrict__ feat,
                        const float* __restrict__ W1,
                        const int* __restrict__ nbr, float* __restrict__ x1) {
    __shared__ int s_nbr[16][27];
    int base = blockIdx.x * 16;
    for (int i = threadIdx.x; i < 16*27; i += 256) {
        int v = i / 27, k = i % 27;
        int n = base + v;
        s_nbr[v][k] = (n < NVOX) ? nbr[n*27 + k] : -1;
    }
    __syncthreads();
    int v = threadIdx.x >> 4, d = threadIdx.x & 15;
    int n = base + v;
    if (n >= NVOX) return;
    float acc = 0.f;
    for (int k = 0; k < 27; ++k) {
        int idx = s_nbr[v][k];
        if (idx < 0) continue;
        const float* f = feat + (size_t)idx * C1;
        const float* w = W1 + k * C1 * 16 + d;
        #pragma unroll 8
        for (int c = 0; c < C1; ++c)
            acc += f[c] * w[c * 16];
    }
    x1[n*16 + d] = fmaxf(acc, 0.f);
}

// ---- subm conv 2: 16 -> 16, ReLU, fp32 out ----
__global__ void k_subm2(const float* __restrict__ x1,
                        const float* __restrict__ W2,
                        const int* __restrict__ nbr, float* __restrict__ x2) {
    __shared__ int   s_nbr[16][27];
    __shared__ float s_w2[27*16*16];
    for (int i = threadIdx.x; i < 27*16*16; i += 256) s_w2[i] = W2[i];
    int base = blockIdx.x * 16;
    for (int i = threadIdx.x; i < 16*27; i += 256) {
        int v = i / 27, k = i % 27;
        int n = base + v;
        s_nbr[v][k] = (n < NVOX) ? nbr[n*27 + k] : -1;
    }
    __syncthreads();
    int v = threadIdx.x >> 4, d = threadIdx.x & 15;
    int n = base + v;
    if (n >= NVOX) return;
    float acc = 0.f;
    for (int k = 0; k < 27; ++k) {
        int idx = s_nbr[v][k];
        if (idx < 0) continue;
        const float* xp = x1 + idx * 16;
        const float* w  = s_w2 + k * 256 + d;
        #pragma unroll
        for (int c = 0; c < 16; ++c) acc += xp[c] * w[c * 16];
    }
    x2[n*16 + d] = fmaxf(acc, 0.f);
}

// ---- valid downsample taps for one axis, from PADDED input coord ----
// ref: o = pcoord - doff (doff in 0..2), valid iff o even and 0 <= o/2 < outdim.
// pcoord >= 1; odd  -> doff=1 only, p=(pcoord-1)/2 always in range.
//             even -> doff=0 (p=h, check <outdim) and doff=2 (p=h-1, h>=1 always).
__device__ __forceinline__ int axis_taps(int pcoord, int outdim, int* ds, int* ps) {
    if (pcoord & 1) { ds[0] = 1; ps[0] = pcoord >> 1; return 1; }
    int h = pcoord >> 1, nu = 0;
    if (h < outdim) { ds[nu] = 0; ps[nu] = h; nu++; }
    ds[nu] = 2; ps[nu] = h - 1; nu++;
    return nu;
}

// ---- stride-2 conv 16 -> 32 as scatter: block = 8 voxels x 32 channels ----
__global__ void k_scatter(const float* __restrict__ x2,
                          const float* __restrict__ W3,
                          const int* __restrict__ coors,
                          float* __restrict__ out) {
    int v = threadIdx.x >> 5, d = threadIdx.x & 31;
    int n = blockIdx.x * 8 + v;
    if (n >= NVOX) return;
    int b  = coors[4*n+0];
    int zp = coors[4*n+1] + 1, yp = coors[4*n+2] + 1, xp = coors[4*n+3] + 1;
    int dz[2], pz[2], dy[2], py[2], dx[2], px[2];
    int nz = axis_taps(zp, DO_, dz, pz);
    int ny = axis_taps(yp, HO_, dy, py);
    int nx = axis_taps(xp, WO_, dx, px);
    const float4* xr = (const float4*)(x2 + (size_t)n * 16);
    float r[16];
    *(float4*)(r + 0)  = xr[0];
    *(float4*)(r + 4)  = xr[1];
    *(float4*)(r + 8)  = xr[2];
    *(float4*)(r + 12) = xr[3];
    int bofs = b * (DO_*HO_*WO_);
    for (int iz = 0; iz < nz; ++iz)
        for (int iy = 0; iy < ny; ++iy)
            for (int ix = 0; ix < nx; ++ix) {
                int k = dz[iz]*9 + dy[iy]*3 + dx[ix];
                int p = bofs + (pz[iz]*HO_ + py[iy])*WO_ + px[ix];
                const float* w = W3 + k*512 + d;   // W3[k][c][d], stride 32 over c
                float acc = 0.f;
                #pragma unroll
                for (int c = 0; c < 16; ++c) acc += r[c] * w[c * 32];
                atomicAdd(out + (size_t)p * 32 + d, acc);
            }
}

// ---- idempotent ReLU over touched positions (duplicates are safe: all adds
// completed in the prior dispatch; concurrent relus write the same value) ----
__global__ void k_relu(const int* __restrict__ coors, float* __restrict__ out) {
    int v = threadIdx.x >> 5, d = threadIdx.x & 31;
    int n = blockIdx.x * 8 + v;
    if (n >= NVOX) return;
    int b  = coors[4*n+0];
    int zp = coors[4*n+1] + 1, yp = coors[4*n+2] + 1, xp = coors[4*n+3] + 1;
    int dz[2], pz[2], dy[2], py[2], dx[2], px[2];
    int nz = axis_taps(zp, DO_, dz, pz);
    int ny = axis_taps(yp, HO_, dy, py);
    int nx = axis_taps(xp, WO_, dx, px);
    int bofs = b * (DO_*HO_*WO_);
    for (int iz = 0; iz < nz; ++iz)
        for (int iy = 0; iy < ny; ++iy)
            for (int ix = 0; ix < nx; ++ix) {
                int p = bofs + (pz[iz]*HO_ + py[iy])*WO_ + px[ix];
                size_t o = (size_t)p * 32 + d;
                out[o] = fmaxf(out[o], 0.f);
            }
}

extern "C" void kernel_launch(void* const* d_in, const int* in_sizes, int n_in,
                              void* d_out, int out_size, void* d_ws, size_t ws_size,
                              hipStream_t stream) {
    const float* feat  = (const float*)d_in[0];  // f32 (N,128)
    const int*   coors = (const int*)d_in[1];    // int32 (N,4)
    const float* W1    = (const float*)d_in[2];  // f32 (27,128,16)
    const float* W2    = (const float*)d_in[3];  // f32 (27,16,16)
    const float* W3    = (const float*)d_in[4];  // f32 (27,16,32)
    float* out = (float*)d_out;                  // f32 (2,21,200,176,32)

    char* ws = (char*)d_ws;
    size_t off = 0;
    unsigned short* grid = (unsigned short*)(ws + off);
    off += (((size_t)GRID_CELLS*2) + 255) & ~(size_t)255;
    int* nbr  = (int*)(ws + off); off += (((size_t)NVOX*27*4)   + 255) & ~(size_t)255;
    float* x1 = (float*)(ws + off); off += (((size_t)NVOX*16*4) + 255) & ~(size_t)255;
    float* x2 = (float*)(ws + off);

    hipMemsetAsync(grid, 0x00, (size_t)GRID_CELLS * 2, stream);     // grid = 0 (empty)
    hipMemsetAsync(out, 0x00, OUT_BYTES, stream);
    k_build<<<(NVOX + 255) / 256, 256, 0, stream>>>(coors, grid);
    k_nbr<<<(NVOX*27 + 255) / 256, 256, 0, stream>>>(coors, grid, nbr);
    k_subm1<<<(NVOX + 15) / 16, 256, 0, stream>>>(feat, W1, nbr, x1);
    k_subm2<<<(NVOX + 15) / 16, 256, 0, stream>>>(x1, W2, nbr, x2);
    k_scatter<<<(NVOX + 7) / 8, 256, 0, stream>>>(x2, W3, coors, out);
    k_relu<<<(NVOX + 7) / 8, 256, 0, stream>>>(coors, out);
}